// Round 12
// baseline (238.888 us; speedup 1.0000x reference)
//
#include <hip/hip_runtime.h>

#define M_DIM 2048
#define K_DIM 4096
#define N_DIM 4096
#define KTILES (K_DIM / 64)

typedef unsigned short u16;
typedef unsigned int u32;
typedef __bf16 bf16x8 __attribute__((ext_vector_type(8)));
typedef float f32x4 __attribute__((ext_vector_type(4)));
typedef float f4 __attribute__((ext_vector_type(4)));
typedef u16 u16x8 __attribute__((ext_vector_type(8)));
typedef u32 u32x4 __attribute__((ext_vector_type(4)));

// fp32 -> bf16 round-to-nearest-even
__device__ __forceinline__ u16 f2bf(float f) {
    unsigned int u = __float_as_uint(f);
    u += 0x7fffu + ((u >> 16) & 1u);
    return (u16)(u >> 16);
}

// pack two fp32 -> (bf16(lo) | bf16(hi)<<16), RNE
__device__ __forceinline__ u32 pack2(float lo, float hi) {
    u32 a = __float_as_uint(lo); a += 0x7fffu + ((a >> 16) & 1u);
    u32 b = __float_as_uint(hi); b += 0x7fffu + ((b >> 16) & 1u);
    return (a >> 16) | (b & 0xffff0000u);
}

// async global->LDS, 16B per lane. LDS dest must be wave-uniform base + lane*16.
__device__ __forceinline__ void load16(const void* g, void* l) {
    __builtin_amdgcn_global_load_lds(
        (__attribute__((address_space(1))) const void*)g,
        (__attribute__((address_space(3))) void*)l,
        16, 0, 0);
}

// --------------- fused prep v4: contiguous reads AND contiguous writes ------
// Bt is stored TILED (gemm-native): BtT[bn][kt] = 32KB tile [row=256][cphys=8]
// of u16x8 chunks, with the gemm's XOR swizzle baked in: tile[row][cphys]
// holds logical k-chunk (cphys ^ (row&7)) of n-row bn*256+row. This makes
// BOTH prep's stores and gemm's load16 sources 1KB-contiguous per wave
// instruction (v2/v3 both wrote 8x128B scatter per instr -> stuck at 2TB/s).
// blocks [0, 1024): one 64(k) x 256(n) tile -> one BtT tile (32KB contig).
// blocks [1024, 3072): x f32 -> bf16, 16 floats/thread (contiguous).
__global__ __launch_bounds__(256) void prep(const float* __restrict__ x,
                                            u16* __restrict__ xb,
                                            const float* __restrict__ W,
                                            const float* __restrict__ Msk,
                                            u16* __restrict__ Bt) {
    const int t = threadIdx.x;
    if (blockIdx.x >= 1024) {
        // ---- conv_x: 16 floats/thread ----
        size_t i = ((size_t)(blockIdx.x - 1024) * 256 + t) * 16;
#pragma unroll
        for (int h = 0; h < 2; ++h) {
            f4 v0 = *(const f4*)(x + i + h * 8);
            f4 v1 = *(const f4*)(x + i + h * 8 + 4);
            u16x8 o;
            o[0] = f2bf(v0[0]); o[1] = f2bf(v0[1]); o[2] = f2bf(v0[2]); o[3] = f2bf(v0[3]);
            o[4] = f2bf(v1[0]); o[5] = f2bf(v1[1]); o[6] = f2bf(v1[2]); o[7] = f2bf(v1[3]);
            *(u16x8*)(xb + i + h * 8) = o;
        }
        return;
    }
    __shared__ __align__(16) float S[64 * 256];     // 64 KB masked-f32 tile

    const int k0 = (blockIdx.x >> 4) * 64;          // 64 k-tiles of 64
    const int n0 = (blockIdx.x & 15) * 256;         // 16 n-tiles of 256
    const int w = t >> 6;                           // wave 0..3
    const int l = t & 63;                           // lane

    // ---- phase 1: row-contiguous 1KB reads; swizzled float4 LDS writes ----
#pragma unroll
    for (int j = 0; j < 16; ++j) {
        const int k = 4 * j + w;
        const size_t g = (size_t)(k0 + k) * N_DIM + n0 + 4 * l;
        f4 wv = *(const f4*)(W + g);
        f4 mv = *(const f4*)(Msk + g);
        f4 o;
        o[0] = mv[0] != 0.f ? wv[0] : 0.f;
        o[1] = mv[1] != 0.f ? wv[1] : 0.f;
        o[2] = mv[2] != 0.f ? wv[2] : 0.f;
        o[3] = mv[3] != 0.f ? wv[3] : 0.f;
        // swizzled chunk: c' = l ^ (k>>3); 16B-aligned b128 write
        *(f4*)(S + k * 256 + ((l ^ (k >> 3)) << 2)) = o;
    }
    __syncthreads();

    // ---- phase 2: column reads (2 lanes/bank), pack, 1KB-contiguous store -
    // Thread (cph=t&7, nn=t>>3); logical chunk clog = cph ^ (nl&7).
    // Wave store: lanes (nn 0..7 x cph 0..7) span 1KB contiguous of the tile.
    const int cph = t & 7;
    const int nn  = t >> 3;
    u16* tbase = Bt + (((size_t)(n0 >> 8) * 64 + (k0 >> 6)) << 14);  // 16384 u16/tile
#pragma unroll
    for (int i = 0; i < 8; ++i) {
        const int nl = nn + 32 * i;                 // tile-local n 0..255
        const int clog = cph ^ (nl & 7);
        float f[8];
#pragma unroll
        for (int j = 0; j < 8; ++j) {
            const int k = 8 * clog + j;             // k>>3 == clog
            f[j] = S[k * 256 + (((nl >> 2) ^ clog) << 2) + (nl & 3)];
        }
        u32x4 o;
        o[0] = pack2(f[0], f[1]);
        o[1] = pack2(f[2], f[3]);
        o[2] = pack2(f[4], f[5]);
        o[3] = pack2(f[6], f[7]);
        *(u32x4*)(tbase + nl * 64 + cph * 8) = o;
    }
}

// --- gemm8 (R6-verified core) with tiled-B addressing -----------------------
// 128m x 256n tile, 2m x 2n x 2k waves, triple-buffer, 1-barrier covered-wait
// loop, XCD swizzle, cross-k LDS reduce epilogue — VERBATIM R6 except the B
// staging source: BtT tiles make every SB load16 read 1KB contiguous and the
// per-block B stream 2MB sequential. LDS content is bit-identical to R6
// (swizzle baked into the tile), so fragments/MFMA/epilogue are untouched.
__global__ __launch_bounds__(512, 2) void gemm8(const u16* __restrict__ A,   // M x K bf16
                                                const u16* __restrict__ Bt,  // tiled
                                                const float* __restrict__ bias,
                                                float* __restrict__ C) {
    __shared__ __align__(16) u16 As[3][128 * 64];   // 3 x 16 KB
    __shared__ __align__(16) u16 Bs[3][256 * 64];   // 3 x 32 KB

    const int t = threadIdx.x;
    // XCD-aware decode: XCD x owns an 8(bm) x 4(bn) chunk -> 16 MB working set
    const int wgid = blockIdx.x;        // 256 WGs, wgid%8 == XCD [m09]
    const int xcd = wgid & 7, c = wgid >> 3;
    const int bm = (xcd & 1) * 8 + (c & 7);     // M/128 = 16
    const int bn = (xcd >> 1) * 4 + (c >> 3);   // N/256 = 16

    const int srow   = t >> 3;
    const int schunk = (t & 7) ^ (srow & 7);
    const u16* gA  = A  + (size_t)(bm * 128 + srow) * K_DIM + schunk * 8;
    const u16* gBt = Bt + ((size_t)bn * 64 << 14) + t * 8;   // tile stream base

    const int lane = t & 63;
    const int wv   = t >> 6;
    const int kh = wv >> 2;             // k-half of every K-tile (0/1)
    const int wq = wv & 3;              // position in 2m x 2n wave grid
    const int mo = (wq >> 1) * 64;      // wave m-origin (0/64)
    const int no = (wq & 1) * 128;      // wave n-origin (0/128)
    const int fr = lane & 15;
    const int q  = lane >> 4;
    const int sw = fr & 7;
    const int colK = (((kh << 2) + q) ^ sw) * 8;

#define SA(buf, kt, j) load16(gA + (size_t)(kt) * 64 + (size_t)(j) * 64 * K_DIM, \
                              (buf) + (j) * 4096 + t * 8)
#define SB(buf, kt, j) load16(gBt + ((size_t)(kt) << 14) + (j) * 4096, \
                              (buf) + (j) * 4096 + t * 8)

    f32x4 acc[4][8] = {};   // [i: m 4x16][j: n 8x16]

    // rotating buffer pointers (register-held; never runtime-indexed)
    u16 *aC = (u16*)As[0], *aN1 = (u16*)As[1], *aN2 = (u16*)As[2];
    u16 *bC = (u16*)Bs[0], *bN1 = (u16*)Bs[1], *bN2 = (u16*)Bs[2];

    // prologue: stage tiles 0 and 1 (12 loads in flight), certify tile 0
    SA(aC, 0, 0);  SA(aC, 0, 1);
    SB(bC, 0, 0);  SB(bC, 0, 1);  SB(bC, 0, 2);  SB(bC, 0, 3);
    SA(aN1, 1, 0); SA(aN1, 1, 1);
    SB(bN1, 1, 0); SB(bN1, 1, 1); SB(bN1, 1, 2); SB(bN1, 1, 3);
    asm volatile("s_waitcnt vmcnt(6)" ::: "memory");
    __builtin_amdgcn_sched_barrier(0);
    __builtin_amdgcn_s_barrier();

    for (int kt = 0; kt < KTILES; ++kt) {
        const int kn = (kt + 2) & (KTILES - 1);   // wrap loads: harmless re-stage
        bf16x8 fA[4], fB0[4], fB1[4];

        // ---- issue ALL fragment reads for tile kt (buffer certified) ------
#pragma unroll
        for (int i = 0; i < 4; ++i)
            fA[i] = *(const bf16x8*)(aC + (mo + i * 16 + fr) * 64 + colK);
#pragma unroll
        for (int j = 0; j < 4; ++j)
            fB0[j] = *(const bf16x8*)(bC + (no + j * 16 + fr) * 64 + colK);
#pragma unroll
        for (int j = 0; j < 4; ++j)
            fB1[j] = *(const bf16x8*)(bC + (no + 64 + j * 16 + fr) * 64 + colK);
        // ---- stage A + B-band0 of tile kt+2 (buf (kt+2)%3: readers done) --
        SA(aN2, kn, 0); SA(aN2, kn, 1); SB(bN2, kn, 0);
        // certify the 8 A/B0 reads (4 B1 reads stay outstanding, DS in-order)
        asm volatile("s_waitcnt lgkmcnt(4)" ::: "memory");
        __builtin_amdgcn_sched_barrier(0);
        __builtin_amdgcn_s_setprio(1);
#pragma unroll
        for (int i = 0; i < 4; ++i)
#pragma unroll
            for (int j = 0; j < 4; ++j)
                acc[i][j] = __builtin_amdgcn_mfma_f32_16x16x32_bf16(
                    fA[i], fB0[j], acc[i][j], 0, 0, 0);
        __builtin_amdgcn_s_setprio(0);
        // certify B1 (covered by the 16-MFMA cluster above)
        asm volatile("s_waitcnt lgkmcnt(0)" ::: "memory");
        __builtin_amdgcn_sched_barrier(0);
        SB(bN2, kn, 1); SB(bN2, kn, 2); SB(bN2, kn, 3);
        __builtin_amdgcn_s_setprio(1);
#pragma unroll
        for (int i = 0; i < 4; ++i)
#pragma unroll
            for (int j = 0; j < 4; ++j)
                acc[i][j + 4] = __builtin_amdgcn_mfma_f32_16x16x32_bf16(
                    fA[i], fB1[j], acc[i][j + 4], 0, 0, 0);
        __builtin_amdgcn_s_setprio(0);
        // certify tile kt+1 (oldest 6 of 12 outstanding); never drains to 0
        asm volatile("s_waitcnt vmcnt(6)" ::: "memory");
        __builtin_amdgcn_sched_barrier(0);
        __builtin_amdgcn_s_barrier();

        // rotate buffers: tile T lives in buf[T % 3]
        u16* tmp;
        tmp = aC; aC = aN1; aN1 = aN2; aN2 = tmp;
        tmp = bC; bC = bN1; bN1 = bN2; bN2 = tmp;
    }

    // ---- epilogue: cross-k-half reduction through LDS ----------------------
    asm volatile("s_waitcnt vmcnt(0)" ::: "memory");
    __builtin_amdgcn_s_barrier();

    // 32 KB region per wq: wq 0..2 -> Bs[wq] (32 KB each), wq 3 -> As (48 KB)
    float* red = (wq == 3) ? (float*)As : (float*)Bs[wq];

    if (kh == 1) {
#pragma unroll
        for (int i = 0; i < 4; ++i)
#pragma unroll
            for (int j = 0; j < 8; ++j)
                *(f32x4*)(red + (i * 8 + j) * 256 + lane * 4) = acc[i][j];
    }
    asm volatile("s_waitcnt lgkmcnt(0)" ::: "memory");
    __builtin_amdgcn_s_barrier();

    if (kh == 0) {
        const int rb = q * 4;
#pragma unroll
        for (int i = 0; i < 4; ++i) {
#pragma unroll
            for (int j = 0; j < 8; ++j) {
                f32x4 other = *(const f32x4*)(red + (i * 8 + j) * 256 + lane * 4);
                int n = bn * 256 + no + j * 16 + fr;
                float bv = bias[n];
#pragma unroll
                for (int r = 0; r < 4; ++r) {
                    int m = bm * 128 + mo + i * 16 + rb + r;
                    C[(size_t)m * N_DIM + n] = acc[i][j][r] + other[r] + bv;
                }
            }
        }
    }
#undef SA
#undef SB
}

extern "C" void kernel_launch(void* const* d_in, const int* in_sizes, int n_in,
                              void* d_out, int out_size, void* d_ws, size_t ws_size,
                              hipStream_t stream) {
    const float* x    = (const float*)d_in[0];  // 2048 x 4096
    const float* mask = (const float*)d_in[1];  // 4096 x 4096
    const float* W    = (const float*)d_in[2];  // 4096 x 4096
    const float* bias = (const float*)d_in[3];  // 4096
    float* out = (float*)d_out;                 // 2048 x 4096

    u16* Bt = (u16*)d_ws;                                   // tiled B: 32 MB
    u16* xb = (u16*)d_ws + (size_t)N_DIM * K_DIM;           // M*K bf16 = 16 MB

    // prep: blocks [0,1024) transpose->tiles, [1024,3072) x-convert
    prep<<<3072, 256, 0, stream>>>(x, xb, W, mask, Bt);
    gemm8<<<256, 512, 0, stream>>>(xb, Bt, bias, out);
}

// Round 13
// 237.400 us; speedup vs baseline: 1.0063x; 1.0063x over previous
//
#include <hip/hip_runtime.h>

#define M_DIM 2048
#define K_DIM 4096
#define N_DIM 4096
#define KTILES (K_DIM / 64)

typedef unsigned short u16;
typedef unsigned int u32;
typedef __bf16 bf16x8 __attribute__((ext_vector_type(8)));
typedef float f32x4 __attribute__((ext_vector_type(4)));
typedef float f4 __attribute__((ext_vector_type(4)));
typedef u16 u16x8 __attribute__((ext_vector_type(8)));
typedef u32 u32x4 __attribute__((ext_vector_type(4)));

// fp32 -> bf16 round-to-nearest-even
__device__ __forceinline__ u16 f2bf(float f) {
    unsigned int u = __float_as_uint(f);
    u += 0x7fffu + ((u >> 16) & 1u);
    return (u16)(u >> 16);
}

// pack two fp32 -> (bf16(lo) | bf16(hi)<<16), RNE
__device__ __forceinline__ u32 pack2(float lo, float hi) {
    u32 a = __float_as_uint(lo); a += 0x7fffu + ((a >> 16) & 1u);
    u32 b = __float_as_uint(hi); b += 0x7fffu + ((b >> 16) & 1u);
    return (a >> 16) | (b & 0xffff0000u);
}

// async global->LDS, 16B per lane. LDS dest must be wave-uniform base + lane*16.
__device__ __forceinline__ void load16(const void* g, void* l) {
    __builtin_amdgcn_global_load_lds(
        (__attribute__((address_space(1))) const void*)g,
        (__attribute__((address_space(3))) void*)l,
        16, 0, 0);
}

// --------------- fused prep v5: 32KB tile -> occupancy-unbound --------------
// v4 analysis: contiguous reads+writes but 64KB LDS capped transpose blocks
// at 2/CU (~17% occupancy) -> too few outstanding loads to cover ~900cyc HBM
// latency -> stuck at 2TB/s. v5 halves the tile to 64(k) x 128(n) = 32KB:
// 5 blocks/CU by LDS, 2048 finer-grained blocks. Reads stay contiguous (wave
// f4-load = two 512B row segments), writes stay fully sequential (16KB per
// block = half of one tiled-Bt gemm tile). Same XOR chunk swizzle; both LDS
// phases <= 2 lanes/bank (free, m136).
// blocks [0, 2048): kt = b>>5, nh = b&31 -> rows [nh*128, nh*128+128) of
//   gemm B-tile (bn = nh>>1, half = nh&1), k-tile kt.
// blocks [2048, 4096): x f32 -> bf16, 16 floats/thread (contiguous).
__global__ __launch_bounds__(256) void prep(const float* __restrict__ x,
                                            u16* __restrict__ xb,
                                            const float* __restrict__ W,
                                            const float* __restrict__ Msk,
                                            u16* __restrict__ Bt) {
    const int t = threadIdx.x;
    if (blockIdx.x >= 2048) {
        // ---- conv_x: 16 floats/thread ----
        size_t i = ((size_t)(blockIdx.x - 2048) * 256 + t) * 16;
#pragma unroll
        for (int h = 0; h < 2; ++h) {
            f4 v0 = *(const f4*)(x + i + h * 8);
            f4 v1 = *(const f4*)(x + i + h * 8 + 4);
            u16x8 o;
            o[0] = f2bf(v0[0]); o[1] = f2bf(v0[1]); o[2] = f2bf(v0[2]); o[3] = f2bf(v0[3]);
            o[4] = f2bf(v1[0]); o[5] = f2bf(v1[1]); o[6] = f2bf(v1[2]); o[7] = f2bf(v1[3]);
            *(u16x8*)(xb + i + h * 8) = o;
        }
        return;
    }
    __shared__ __align__(16) float S[64 * 128];     // 32 KB masked-f32 tile

    const int kt = blockIdx.x >> 5;                 // 0..63
    const int nh = blockIdx.x & 31;                 // 0..31 (128-row halves)
    const int k0 = kt * 64;
    const int n0 = nh * 128;
    const int w = t >> 6;                           // wave 0..3
    const int l = t & 63;                           // lane

    // ---- phase 1: contiguous reads (2x512B per instr); swizzled LDS write -
    // iteration it: wave w covers rows k = it*8 + w*2 + (l>>5), cols (l&31)*4
#pragma unroll
    for (int it = 0; it < 8; ++it) {
        const int k = it * 8 + w * 2 + (l >> 5);
        const int c = l & 31;                       // f4-chunk within row
        const size_t g = (size_t)(k0 + k) * N_DIM + n0 + 4 * c;
        f4 wv = *(const f4*)(W + g);
        f4 mv = *(const f4*)(Msk + g);
        f4 o;
        o[0] = mv[0] != 0.f ? wv[0] : 0.f;
        o[1] = mv[1] != 0.f ? wv[1] : 0.f;
        o[2] = mv[2] != 0.f ? wv[2] : 0.f;
        o[3] = mv[3] != 0.f ? wv[3] : 0.f;
        // swizzled chunk: c' = c ^ (k>>3); 16B-aligned b128 write
        *(f4*)(S + k * 128 + ((c ^ (k >> 3)) << 2)) = o;
    }
    __syncthreads();

    // ---- phase 2: column reads (2 lanes/bank), pack, sequential store -----
    // Thread (cph=t&7, nn=t>>3); nl = nn + 32i covers 0..127.
    // Stored chunk at [row=half*128+nl][cph] = logical cph ^ (row&7), the
    // exact content gemm8's tiled SB expects (row&7 == nl&7).
    const int cph = t & 7;
    const int nn  = t >> 3;
    u16* tb = Bt + (((size_t)(nh >> 1) * 64 + kt) << 14) + (size_t)(nh & 1) * 8192;
#pragma unroll
    for (int i = 0; i < 4; ++i) {
        const int nl = nn + 32 * i;                 // 0..127
        const int clog = cph ^ (nl & 7);
        float f[8];
#pragma unroll
        for (int j = 0; j < 8; ++j) {
            const int k = 8 * clog + j;             // k>>3 == clog
            f[j] = S[k * 128 + (((nl >> 2) ^ clog) << 2) + (nl & 3)];
        }
        u32x4 o;
        o[0] = pack2(f[0], f[1]);
        o[1] = pack2(f[2], f[3]);
        o[2] = pack2(f[4], f[5]);
        o[3] = pack2(f[6], f[7]);
        *(u32x4*)(tb + nl * 64 + cph * 8) = o;
    }
}

// --- gemm8 (R6-verified core, R12 tiled-B addressing) — VERBATIM ------------
// 128m x 256n tile, 2m x 2n x 2k waves, triple-buffer, 1-barrier covered-wait
// loop, XCD swizzle, cross-k LDS reduce epilogue. 65.2us / util 42 / confl 0.
__global__ __launch_bounds__(512, 2) void gemm8(const u16* __restrict__ A,   // M x K bf16
                                                const u16* __restrict__ Bt,  // tiled
                                                const float* __restrict__ bias,
                                                float* __restrict__ C) {
    __shared__ __align__(16) u16 As[3][128 * 64];   // 3 x 16 KB
    __shared__ __align__(16) u16 Bs[3][256 * 64];   // 3 x 32 KB

    const int t = threadIdx.x;
    // XCD-aware decode: XCD x owns an 8(bm) x 4(bn) chunk -> 16 MB working set
    const int wgid = blockIdx.x;        // 256 WGs, wgid%8 == XCD [m09]
    const int xcd = wgid & 7, c = wgid >> 3;
    const int bm = (xcd & 1) * 8 + (c & 7);     // M/128 = 16
    const int bn = (xcd >> 1) * 4 + (c >> 3);   // N/256 = 16

    const int srow   = t >> 3;
    const int schunk = (t & 7) ^ (srow & 7);
    const u16* gA  = A  + (size_t)(bm * 128 + srow) * K_DIM + schunk * 8;
    const u16* gBt = Bt + ((size_t)bn * 64 << 14) + t * 8;   // tile stream base

    const int lane = t & 63;
    const int wv   = t >> 6;
    const int kh = wv >> 2;             // k-half of every K-tile (0/1)
    const int wq = wv & 3;              // position in 2m x 2n wave grid
    const int mo = (wq >> 1) * 64;      // wave m-origin (0/64)
    const int no = (wq & 1) * 128;      // wave n-origin (0/128)
    const int fr = lane & 15;
    const int q  = lane >> 4;
    const int sw = fr & 7;
    const int colK = (((kh << 2) + q) ^ sw) * 8;

#define SA(buf, kt, j) load16(gA + (size_t)(kt) * 64 + (size_t)(j) * 64 * K_DIM, \
                              (buf) + (j) * 4096 + t * 8)
#define SB(buf, kt, j) load16(gBt + ((size_t)(kt) << 14) + (j) * 4096, \
                              (buf) + (j) * 4096 + t * 8)

    f32x4 acc[4][8] = {};   // [i: m 4x16][j: n 8x16]

    // rotating buffer pointers (register-held; never runtime-indexed)
    u16 *aC = (u16*)As[0], *aN1 = (u16*)As[1], *aN2 = (u16*)As[2];
    u16 *bC = (u16*)Bs[0], *bN1 = (u16*)Bs[1], *bN2 = (u16*)Bs[2];

    // prologue: stage tiles 0 and 1 (12 loads in flight), certify tile 0
    SA(aC, 0, 0);  SA(aC, 0, 1);
    SB(bC, 0, 0);  SB(bC, 0, 1);  SB(bC, 0, 2);  SB(bC, 0, 3);
    SA(aN1, 1, 0); SA(aN1, 1, 1);
    SB(bN1, 1, 0); SB(bN1, 1, 1); SB(bN1, 1, 2); SB(bN1, 1, 3);
    asm volatile("s_waitcnt vmcnt(6)" ::: "memory");
    __builtin_amdgcn_sched_barrier(0);
    __builtin_amdgcn_s_barrier();

    for (int kt = 0; kt < KTILES; ++kt) {
        const int kn = (kt + 2) & (KTILES - 1);   // wrap loads: harmless re-stage
        bf16x8 fA[4], fB0[4], fB1[4];

        // ---- issue ALL fragment reads for tile kt (buffer certified) ------
#pragma unroll
        for (int i = 0; i < 4; ++i)
            fA[i] = *(const bf16x8*)(aC + (mo + i * 16 + fr) * 64 + colK);
#pragma unroll
        for (int j = 0; j < 4; ++j)
            fB0[j] = *(const bf16x8*)(bC + (no + j * 16 + fr) * 64 + colK);
#pragma unroll
        for (int j = 0; j < 4; ++j)
            fB1[j] = *(const bf16x8*)(bC + (no + 64 + j * 16 + fr) * 64 + colK);
        // ---- stage A + B-band0 of tile kt+2 (buf (kt+2)%3: readers done) --
        SA(aN2, kn, 0); SA(aN2, kn, 1); SB(bN2, kn, 0);
        // certify the 8 A/B0 reads (4 B1 reads stay outstanding, DS in-order)
        asm volatile("s_waitcnt lgkmcnt(4)" ::: "memory");
        __builtin_amdgcn_sched_barrier(0);
        __builtin_amdgcn_s_setprio(1);
#pragma unroll
        for (int i = 0; i < 4; ++i)
#pragma unroll
            for (int j = 0; j < 4; ++j)
                acc[i][j] = __builtin_amdgcn_mfma_f32_16x16x32_bf16(
                    fA[i], fB0[j], acc[i][j], 0, 0, 0);
        __builtin_amdgcn_s_setprio(0);
        // certify B1 (covered by the 16-MFMA cluster above)
        asm volatile("s_waitcnt lgkmcnt(0)" ::: "memory");
        __builtin_amdgcn_sched_barrier(0);
        SB(bN2, kn, 1); SB(bN2, kn, 2); SB(bN2, kn, 3);
        __builtin_amdgcn_s_setprio(1);
#pragma unroll
        for (int i = 0; i < 4; ++i)
#pragma unroll
            for (int j = 0; j < 4; ++j)
                acc[i][j + 4] = __builtin_amdgcn_mfma_f32_16x16x32_bf16(
                    fA[i], fB1[j], acc[i][j + 4], 0, 0, 0);
        __builtin_amdgcn_s_setprio(0);
        // certify tile kt+1 (oldest 6 of 12 outstanding); never drains to 0
        asm volatile("s_waitcnt vmcnt(6)" ::: "memory");
        __builtin_amdgcn_sched_barrier(0);
        __builtin_amdgcn_s_barrier();

        // rotate buffers: tile T lives in buf[T % 3]
        u16* tmp;
        tmp = aC; aC = aN1; aN1 = aN2; aN2 = tmp;
        tmp = bC; bC = bN1; bN1 = bN2; bN2 = tmp;
    }

    // ---- epilogue: cross-k-half reduction through LDS ----------------------
    asm volatile("s_waitcnt vmcnt(0)" ::: "memory");
    __builtin_amdgcn_s_barrier();

    // 32 KB region per wq: wq 0..2 -> Bs[wq] (32 KB each), wq 3 -> As (48 KB)
    float* red = (wq == 3) ? (float*)As : (float*)Bs[wq];

    if (kh == 1) {
#pragma unroll
        for (int i = 0; i < 4; ++i)
#pragma unroll
            for (int j = 0; j < 8; ++j)
                *(f32x4*)(red + (i * 8 + j) * 256 + lane * 4) = acc[i][j];
    }
    asm volatile("s_waitcnt lgkmcnt(0)" ::: "memory");
    __builtin_amdgcn_s_barrier();

    if (kh == 0) {
        const int rb = q * 4;
#pragma unroll
        for (int i = 0; i < 4; ++i) {
#pragma unroll
            for (int j = 0; j < 8; ++j) {
                f32x4 other = *(const f32x4*)(red + (i * 8 + j) * 256 + lane * 4);
                int n = bn * 256 + no + j * 16 + fr;
                float bv = bias[n];
#pragma unroll
                for (int r = 0; r < 4; ++r) {
                    int m = bm * 128 + mo + i * 16 + rb + r;
                    C[(size_t)m * N_DIM + n] = acc[i][j][r] + other[r] + bv;
                }
            }
        }
    }
#undef SA
#undef SB
}

extern "C" void kernel_launch(void* const* d_in, const int* in_sizes, int n_in,
                              void* d_out, int out_size, void* d_ws, size_t ws_size,
                              hipStream_t stream) {
    const float* x    = (const float*)d_in[0];  // 2048 x 4096
    const float* mask = (const float*)d_in[1];  // 4096 x 4096
    const float* W    = (const float*)d_in[2];  // 4096 x 4096
    const float* bias = (const float*)d_in[3];  // 4096
    float* out = (float*)d_out;                 // 2048 x 4096

    u16* Bt = (u16*)d_ws;                                   // tiled B: 32 MB
    u16* xb = (u16*)d_ws + (size_t)N_DIM * K_DIM;           // M*K bf16 = 16 MB

    // prep: blocks [0,2048) transpose->tiles, [2048,4096) x-convert
    prep<<<4096, 256, 0, stream>>>(x, xb, W, mask, Bt);
    gemm8<<<256, 512, 0, stream>>>(xb, Bt, bias, out);
}